// Round 12
// baseline (234.323 us; speedup 1.0000x reference)
//
#include <hip/hip_runtime.h>
#include <math.h>
#include <stdint.h>

#define N_NODE 100000
#define N_EDGE 1000000
#define DIM    64
#define NB     256
#define NVOCAB 401
#define AGG_WAVES 8192
#define NSTREAM (AGG_WAVES * 4)           // quarter-wave node streams

// bucket decomposition: bucket = obj >> 9 (512 nodes/bucket).
#define BSH    9
#define BMSK   511
#define NBKT   ((N_NODE + BMSK) >> BSH)   // 196
#define CHKE   1024                       // edges per chunk
#define NCHK   ((N_EDGE + CHKE - 1) / CHKE)   // 977
#define SCAN_TOT (NBKT * NCHK)            // 191492
#define SCANA_GRID ((SCAN_TOT + 1023) / 1024) // 188

typedef short short8  __attribute__((ext_vector_type(8)));
typedef float floatx4 __attribute__((ext_vector_type(4)));
typedef unsigned short ushort_t;

__device__ inline unsigned short f2bf_rne(float f)
{
    unsigned u = __float_as_uint(f);
    unsigned r = u + 0x7FFF + ((u >> 16) & 1);
    return (unsigned short)(r >> 16);
}
__device__ inline float bflo(unsigned u) { return __uint_as_float(u << 16); }
__device__ inline float bfhi(unsigned u) { return __uint_as_float(u & 0xFFFF0000u); }
__device__ inline unsigned us16(short s) { return (unsigned)(unsigned short)s; }

__device__ inline void split8(float4 v0, float4 v1, short8& hi, short8& lo)
{
    float f[8] = {v0.x, v0.y, v0.z, v0.w, v1.x, v1.y, v1.z, v1.w};
    #pragma unroll
    for (int j = 0; j < 8; ++j) {
        unsigned u = __float_as_uint(f[j]);
        unsigned r = u + 0x7FFF + ((u >> 16) & 1);
        unsigned short h = (unsigned short)(r >> 16);
        float hf = __uint_as_float(((unsigned)h) << 16);
        float l  = f[j] - hf;
        unsigned u2 = __float_as_uint(l);
        unsigned r2 = u2 + 0x7FFF + ((u2 >> 16) & 1);
        hi[j] = (short)h;
        lo[j] = (short)(r2 >> 16);
    }
}

// ---------------------------------------------------------------------------
// init: pre-split the 4 weight matrices into bf16 hi/lo tables.
// ---------------------------------------------------------------------------
#define INIT_GRID ((4 * 4096 + 255) / 256)

__global__ __launch_bounds__(256) void init_kernel(
    const float* __restrict__ Ws, const float* __restrict__ Wr,
    const float* __restrict__ Wqr, const float* __restrict__ Wh,
    ushort_t* __restrict__ wsp)
{
    int tid = blockIdx.x * 256 + threadIdx.x;
    if (tid < 4 * 4096) {
        int w = tid >> 12, e = tid & 4095;
        const float* src = (w == 0) ? Ws : (w == 1) ? Wr : (w == 2) ? Wqr : Wh;
        float f = src[e];
        unsigned u = __float_as_uint(f);
        unsigned r = u + 0x7FFF + ((u >> 16) & 1);
        unsigned short h = (unsigned short)(r >> 16);
        float hf = __uint_as_float(((unsigned)h) << 16);
        float l  = f - hf;
        unsigned u2 = __float_as_uint(l);
        unsigned r2 = u2 + 0x7FFF + ((u2 >> 16) & 1);
        wsp[w * 8192 + e]        = h;
        wsp[w * 8192 + 4096 + e] = (unsigned short)(r2 >> 16);
    }
}

// ---------------------------------------------------------------------------
// gemm64p body (fp32 A, PRE-SPLIT bf16 W). Swapped operands -> packed stores.
// out_mode: 0 fp32 | 1 fp32+relu | 2 bf16 | 3 bf16 + bf16(X) copy to Y2 |
//           4 INTERLEAVED hh: pre at row[(f>>2)*8+(f&3)], bf16(X) at +4.
//           (mode 4: Yv = hh base, row stride 128 ushorts = 256B)
// ---------------------------------------------------------------------------
__device__ void gemm64p_body(
    const float* __restrict__ X,
    const int*   __restrict__ idx,
    const ushort_t* __restrict__ Whi,
    const ushort_t* __restrict__ Wlo,
    const float* __restrict__ bias,
    void* __restrict__ Yv,
    ushort_t* __restrict__ Y2,
    int R, int out_mode, int blk)
{
    int wave = threadIdx.x >> 6;
    int lane = threadIdx.x & 63;
    int m    = lane & 15;
    int quad = lane >> 4;
    int r0   = blk * 64 + wave * 16;

    int r = r0 + m;
    int src = (r < R) ? (idx ? idx[r] : r) : 0;
    const float* xrow = X + (size_t)src * DIM + quad * 8;

    float4 a0[2], a1[2];
    #pragma unroll
    for (int c = 0; c < 2; ++c) {
        a0[c] = *(const float4*)(xrow + 32 * c);
        a1[c] = *(const float4*)(xrow + 32 * c + 4);
    }
    short8 ah[2], al[2];
    #pragma unroll
    for (int c = 0; c < 2; ++c) split8(a0[c], a1[c], ah[c], al[c]);

    if (out_mode == 3 && r < R) {
        #pragma unroll
        for (int c = 0; c < 2; ++c)
            *(short8*)(Y2 + (size_t)r * DIM + 32 * c + quad * 8) = ah[c];
    }
    if (out_mode == 4 && r < R) {
        ushort_t* hhrow = (ushort_t*)Yv + (size_t)r * 128;
        #pragma unroll
        for (int c = 0; c < 2; ++c) {
            int fb = quad * 2 + 8 * c;
            uint2 o1, o2;
            o1.x = us16(ah[c][0]) | (us16(ah[c][1]) << 16);
            o1.y = us16(ah[c][2]) | (us16(ah[c][3]) << 16);
            o2.x = us16(ah[c][4]) | (us16(ah[c][5]) << 16);
            o2.y = us16(ah[c][6]) | (us16(ah[c][7]) << 16);
            *(uint2*)(hhrow + fb * 8 + 4)       = o1;
            *(uint2*)(hhrow + (fb + 1) * 8 + 4) = o2;
        }
    }

    floatx4 acc[4] = {{0,0,0,0},{0,0,0,0},{0,0,0,0},{0,0,0,0}};
    #pragma unroll
    for (int g = 0; g < 4; ++g) {
        const ushort_t* whrow = Whi + (size_t)(g * 16 + m) * DIM + quad * 8;
        const ushort_t* wlrow = Wlo + (size_t)(g * 16 + m) * DIM + quad * 8;
        #pragma unroll
        for (int c = 0; c < 2; ++c) {
            short8 bh = *(const short8*)(whrow + 32 * c);
            short8 bl = *(const short8*)(wlrow + 32 * c);
            acc[g] = __builtin_amdgcn_mfma_f32_16x16x32_bf16(bh, ah[c], acc[g], 0, 0, 0);
            acc[g] = __builtin_amdgcn_mfma_f32_16x16x32_bf16(bl, ah[c], acc[g], 0, 0, 0);
            acc[g] = __builtin_amdgcn_mfma_f32_16x16x32_bf16(bh, al[c], acc[g], 0, 0, 0);
        }
    }

    if (r < R) {
        #pragma unroll
        for (int g = 0; g < 4; ++g) {
            float4 bv = make_float4(0.f, 0.f, 0.f, 0.f);
            if (bias) bv = *(const float4*)(bias + g * 16 + quad * 4);
            float v0 = acc[g][0] + bv.x;
            float v1 = acc[g][1] + bv.y;
            float v2 = acc[g][2] + bv.z;
            float v3 = acc[g][3] + bv.w;
            if (out_mode == 1) {
                v0 = fmaxf(v0, 0.f); v1 = fmaxf(v1, 0.f);
                v2 = fmaxf(v2, 0.f); v3 = fmaxf(v3, 0.f);
            }
            if (out_mode == 4) {
                ushort_t* hhrow = (ushort_t*)Yv + (size_t)r * 128;
                int fblk = g * 4 + quad;
                uint2 o;
                o.x = (unsigned)f2bf_rne(v0) | ((unsigned)f2bf_rne(v1) << 16);
                o.y = (unsigned)f2bf_rne(v2) | ((unsigned)f2bf_rne(v3) << 16);
                *(uint2*)(hhrow + fblk * 8) = o;
            } else if (out_mode >= 2) {
                uint2 o;
                o.x = (unsigned)f2bf_rne(v0) | ((unsigned)f2bf_rne(v1) << 16);
                o.y = (unsigned)f2bf_rne(v2) | ((unsigned)f2bf_rne(v3) << 16);
                *(uint2*)((ushort_t*)Yv + (size_t)r * DIM + g * 16 + quad * 4) = o;
            } else {
                *(float4*)((float*)Yv + (size_t)r * DIM + g * 16 + quad * 4) =
                    make_float4(v0, v1, v2, v3);
            }
        }
    }
}

// ---------------------------------------------------------------------------
// Final gemm, bf16 A, pre-split W: Y[r] = relu( A[r] @ W^T ), fp32 out.
// ---------------------------------------------------------------------------
__global__ __launch_bounds__(256) void gemm64p_bf16A_kernel(
    const ushort_t* __restrict__ A,
    const ushort_t* __restrict__ Whi,
    const ushort_t* __restrict__ Wlo,
    float* __restrict__ Y, int R)
{
    int wave = threadIdx.x >> 6;
    int lane = threadIdx.x & 63;
    int m    = lane & 15;
    int quad = lane >> 4;
    int r0   = blockIdx.x * 64 + wave * 16;

    int r = r0 + m;
    int src = (r < R) ? r : 0;
    short8 a8[2];
    #pragma unroll
    for (int c = 0; c < 2; ++c)
        a8[c] = *(const short8*)(A + (size_t)src * DIM + 32 * c + quad * 8);

    floatx4 acc[4] = {{0,0,0,0},{0,0,0,0},{0,0,0,0},{0,0,0,0}};
    #pragma unroll
    for (int g = 0; g < 4; ++g) {
        const ushort_t* whrow = Whi + (size_t)(g * 16 + m) * DIM + quad * 8;
        const ushort_t* wlrow = Wlo + (size_t)(g * 16 + m) * DIM + quad * 8;
        #pragma unroll
        for (int c = 0; c < 2; ++c) {
            short8 bh = *(const short8*)(whrow + 32 * c);
            short8 bl = *(const short8*)(wlrow + 32 * c);
            acc[g] = __builtin_amdgcn_mfma_f32_16x16x32_bf16(bh, a8[c], acc[g], 0, 0, 0);
            acc[g] = __builtin_amdgcn_mfma_f32_16x16x32_bf16(bl, a8[c], acc[g], 0, 0, 0);
        }
    }

    if (r < R) {
        #pragma unroll
        for (int g = 0; g < 4; ++g) {
            *(float4*)(Y + (size_t)r * DIM + g * 16 + quad * 4) =
                make_float4(fmaxf(acc[g][0], 0.f), fmaxf(acc[g][1], 0.f),
                            fmaxf(acc[g][2], 0.f), fmaxf(acc[g][3], 0.f));
        }
    }
}

// ---------------------------------------------------------------------------
// OLD fp32-W gemm body (fallback path only).
// ---------------------------------------------------------------------------
__device__ void gemm64_body(
    const float* __restrict__ X,
    const int*   __restrict__ idx,
    const float* __restrict__ W,
    const float* __restrict__ bias,
    void* __restrict__ Yv,
    ushort_t* __restrict__ Y2,
    int R, int out_mode, int blk)
{
    int wave = threadIdx.x >> 6;
    int lane = threadIdx.x & 63;
    int m    = lane & 15;
    int quad = lane >> 4;
    int r0   = blk * 64 + wave * 16;

    int r = r0 + m;
    int src = (r < R) ? (idx ? idx[r] : r) : 0;
    const float* xrow = X + (size_t)src * DIM + quad * 8;

    float4 a0[2], a1[2];
    #pragma unroll
    for (int c = 0; c < 2; ++c) {
        a0[c] = *(const float4*)(xrow + 32 * c);
        a1[c] = *(const float4*)(xrow + 32 * c + 4);
    }
    short8 ah[2], al[2];
    #pragma unroll
    for (int c = 0; c < 2; ++c) split8(a0[c], a1[c], ah[c], al[c]);

    if (out_mode == 3 && r < R) {
        #pragma unroll
        for (int c = 0; c < 2; ++c)
            *(short8*)(Y2 + (size_t)r * DIM + 32 * c + quad * 8) = ah[c];
    }

    floatx4 acc[4] = {{0,0,0,0},{0,0,0,0},{0,0,0,0},{0,0,0,0}};
    #pragma unroll
    for (int g = 0; g < 4; ++g) {
        const float* wrow = W + (size_t)(g * 16 + m) * DIM + quad * 8;
        #pragma unroll
        for (int c = 0; c < 2; ++c) {
            float4 b0 = *(const float4*)(wrow + 32 * c);
            float4 b1 = *(const float4*)(wrow + 32 * c + 4);
            short8 bh, bl;
            split8(b0, b1, bh, bl);
            acc[g] = __builtin_amdgcn_mfma_f32_16x16x32_bf16(ah[c], bh, acc[g], 0, 0, 0);
            acc[g] = __builtin_amdgcn_mfma_f32_16x16x32_bf16(ah[c], bl, acc[g], 0, 0, 0);
            acc[g] = __builtin_amdgcn_mfma_f32_16x16x32_bf16(al[c], bh, acc[g], 0, 0, 0);
        }
    }

    #pragma unroll
    for (int g = 0; g < 4; ++g) {
        float bv = bias ? bias[g * 16 + m] : 0.0f;
        #pragma unroll
        for (int reg = 0; reg < 4; ++reg) {
            int rr = r0 + quad * 4 + reg;
            if (rr < R) {
                float v = acc[g][reg] + bv;
                if (out_mode == 1) v = fmaxf(v, 0.0f);
                if (out_mode >= 2)
                    ((ushort_t*)Yv)[(size_t)rr * DIM + g * 16 + m] = f2bf_rne(v);
                else
                    ((float*)Yv)[(size_t)rr * DIM + g * 16 + m] = v;
            }
        }
    }
}

__global__ __launch_bounds__(256) void gemm64_kernel(
    const float* __restrict__ X, const int* __restrict__ idx,
    const float* __restrict__ W, const float* __restrict__ bias,
    void* __restrict__ Yv, ushort_t* __restrict__ Y2, int R, int out_mode)
{
    gemm64_body(X, idx, W, bias, Yv, Y2, R, out_mode, blockIdx.x);
}

// ---------------------------------------------------------------------------
// prepcount: blocks [0,977): edge chunks -> epack + per-chunk LDS histogram
// over 196 obj-buckets (plain stores, ZERO global atomics). Rest: gemms.
// Ws-gemm writes the INTERLEAVED hh table (mode 4).
// ---------------------------------------------------------------------------
#define G1 ((N_NODE + 63) / 64)            // 1563
#define G2 ((NVOCAB + 63) / 64)            // 7
#define G3 (NB / 64)                       // 4
#define GSMALL (G2 + G3)                   // 11
#define PREPC_GRID (NCHK + GSMALL + G1)    // 2551

__global__ __launch_bounds__(256) void prepcount_kernel(
    const float* __restrict__ hidden,
    const float* __restrict__ rela,
    const int*   __restrict__ q_rel,
    const ushort_t* __restrict__ wsp,
    const float* __restrict__ Wqr_b,
    ushort_t* __restrict__ hh,
    ushort_t* __restrict__ rel_preb,
    ushort_t* __restrict__ relab,
    ushort_t* __restrict__ qr_preb,
    const int* __restrict__ edges,
    int2* __restrict__ epack,
    int* __restrict__ histBB)          // [NCHK][NBKT]
{
    int b = blockIdx.x;
    if (b < NCHK) {
        __shared__ unsigned cnt[NBKT];
        if (threadIdx.x < NBKT) cnt[threadIdx.x] = 0;
        __syncthreads();
        int base = b * CHKE + threadIdx.x;
        #pragma unroll
        for (int k = 0; k < 4; ++k) {
            int e = base + k * 256;
            if (e < N_EDGE) {
                int2 ab = *(const int2*)(edges + (size_t)e * 6);      // (r_idx,0)
                int2 cd = *(const int2*)(edges + (size_t)e * 6 + 2);  // (rel,0)
                int2 ef = *(const int2*)(edges + (size_t)e * 6 + 4);  // (sub,obj)
                epack[e] = make_int2(ef.x | (cd.x << 17), ef.y | (ab.x << 17));
                atomicAdd(&cnt[ef.y >> BSH], 1u);                     // LDS only
            }
        }
        __syncthreads();
        if (threadIdx.x < NBKT)
            histBB[b * NBKT + threadIdx.x] = (int)cnt[threadIdx.x];
    } else if (b < NCHK + G2) {
        gemm64p_body(rela, nullptr, wsp + 1 * 8192, wsp + 1 * 8192 + 4096,
                     nullptr, rel_preb, relab, NVOCAB, 3, b - NCHK);
    } else if (b < NCHK + GSMALL) {
        gemm64p_body(rela, q_rel, wsp + 2 * 8192, wsp + 2 * 8192 + 4096,
                     Wqr_b, qr_preb, nullptr, NB, 2, b - NCHK - G2);
    } else {
        gemm64p_body(hidden, nullptr, wsp, wsp + 4096,
                     nullptr, hh, nullptr, N_NODE, 4, b - NCHK - GSMALL);
    }
}

// ---------------------------------------------------------------------------
// Scan pipeline over histBB (bin-major m = bin*NCHK + chunk).
// ---------------------------------------------------------------------------
__global__ __launch_bounds__(1024) void scanA_kernel(
    const int* __restrict__ histBB, int* __restrict__ offs2,
    int* __restrict__ partialA)
{
    __shared__ int s[1024];
    int t = threadIdx.x;
    int m = blockIdx.x * 1024 + t;
    int v = 0;
    if (m < SCAN_TOT) {
        int bin = m / NCHK, ch = m - bin * NCHK;
        v = histBB[ch * NBKT + bin];
    }
    s[t] = v;
    __syncthreads();
    for (int off = 1; off < 1024; off <<= 1) {
        int add = (t >= off) ? s[t - off] : 0;
        __syncthreads();
        s[t] += add;
        __syncthreads();
    }
    if (m < SCAN_TOT) offs2[m] = s[t] - v;   // local exclusive
    if (t == 1023) partialA[blockIdx.x] = s[1023];
}

__global__ __launch_bounds__(1024) void scanC_kernel(
    int* __restrict__ offs2, const int* __restrict__ partialA,
    int* __restrict__ bstart)
{
    __shared__ int s[1024];
    __shared__ int pbase_s;
    int t = threadIdx.x;
    int pb = (t < (int)blockIdx.x) ? partialA[t] : 0;   // SCANA_GRID <= 1024
    s[t] = pb;
    __syncthreads();
    for (int off = 1024 / 2; off; off >>= 1) {
        if (t < off) s[t] += s[t + off];
        __syncthreads();
    }
    if (t == 0) pbase_s = s[0];
    __syncthreads();
    int pbase = pbase_s;

    int m = blockIdx.x * 1024 + t;
    if (m < SCAN_TOT) {
        int val = offs2[m] + pbase;
        offs2[m] = val;
        int bin = m / NCHK, ch = m - bin * NCHK;
        if (ch == 0) bstart[bin] = val;
    }
    if (blockIdx.x == 0 && t == 0) bstart[NBKT] = N_EDGE;
}

// ---------------------------------------------------------------------------
// scatter: PURE PERMUTATION (alpha math moved into agg). Reads epack
// coalesced, LDS bucket cursors, scattered 8B writes. No gathers, no score.
// Record: w0 = sub | (obj&511)<<17 ; w1 = rel | r_idx<<9.
// ---------------------------------------------------------------------------
__global__ __launch_bounds__(256) void scatter_kernel(
    const int2* __restrict__ epack,
    const int*  __restrict__ offs2,
    int2*       __restrict__ csr2)
{
    __shared__ int offL[NBKT];
    int blk = blockIdx.x;
    if (threadIdx.x < NBKT)
        offL[threadIdx.x] = offs2[threadIdx.x * NCHK + blk];
    __syncthreads();
    int base = blk * CHKE + threadIdx.x;
    #pragma unroll
    for (int k = 0; k < 4; ++k) {
        int e = base + k * 256;
        if (e < N_EDGE) {
            int2 ep = epack[e];
            int sub = ep.x & 0x1FFFF;
            int rl  = (int)((unsigned)ep.x >> 17);
            int ob  = ep.y & 0x1FFFF;
            int ri  = (int)((unsigned)ep.y >> 17);
            int slot = atomicAdd(&offL[ob >> BSH], 1);
            csr2[slot] = make_int2(sub | ((ob & BMSK) << 17), rl | (ri << 9));
        }
    }
}

// ---------------------------------------------------------------------------
// node_sort: block = bucket (512 nodes, 512 threads). Bucket-sorted csr2 ->
// node-sorted csr3 + per-node offs. LDS counting sort over 512 node slots.
// ---------------------------------------------------------------------------
__global__ __launch_bounds__(512) void node_sort_kernel(
    const int2* __restrict__ csr2,
    const int*  __restrict__ bstart,
    int2* __restrict__ csr3,
    int*  __restrict__ offs)
{
    __shared__ int cnt[512], incl[512];
    int b = blockIdx.x;
    int start = bstart[b];
    int end   = bstart[b + 1];
    int len   = end - start;

    cnt[threadIdx.x] = 0;
    __syncthreads();
    for (int t = threadIdx.x; t < len; t += 512) {
        unsigned x = (unsigned)csr2[start + t].x;
        atomicAdd(&cnt[x >> 17], 1);
    }
    __syncthreads();
    incl[threadIdx.x] = cnt[threadIdx.x];
    __syncthreads();
    for (int off = 1; off < 512; off <<= 1) {
        int add = ((int)threadIdx.x >= off) ? incl[threadIdx.x - off] : 0;
        __syncthreads();
        incl[threadIdx.x] += add;
        __syncthreads();
    }
    {
        int excl = incl[threadIdx.x] - cnt[threadIdx.x];
        int n = (b << BSH) + threadIdx.x;
        if (n < N_NODE) offs[n] = start + excl;
        cnt[threadIdx.x] = excl;           // becomes cursor
    }
    if (b == 0 && threadIdx.x == 0) offs[N_NODE] = N_EDGE;
    if (b == 0 && threadIdx.x < 32) csr3[N_EDGE + threadIdx.x] = make_int2(0, 0);
    __syncthreads();
    for (int t = threadIdx.x; t < len; t += 512) {
        int2 ed = csr2[start + t];
        int row = (int)((unsigned)ed.x >> 17);
        int pos = start + atomicAdd(&cnt[row], 1);
        csr3[pos] = ed;
    }
}

// ---------------------------------------------------------------------------
// Aggregation v10: quarter-wave streams (v9) + FUSED alpha. Per edge: ONE
// uint4 gather of the interleaved hh row (pre[f0..3] | hid[f0..3]) -- the
// same sub index that previously drove TWO separate 128B gather passes
// (alpha_scatter's hsWs + agg's hidb). Score t reduced over the 16-lane
// group (4 shfl), alpha = sigmoid fp32 (better than old f16 round-trip).
// ---------------------------------------------------------------------------
__global__ __launch_bounds__(256) void agg_kernel(
    const int2*     __restrict__ csr3,
    const int*      __restrict__ offs,
    const ushort_t* __restrict__ hh,       // [N_NODE][128] interleaved
    const ushort_t* __restrict__ rel_preb,
    const ushort_t* __restrict__ qr_preb,
    const ushort_t* __restrict__ relab,
    const float*    __restrict__ wattn,
    ushort_t* __restrict__ aggb)           // bf16 [N_NODE][64]
{
    int l  = threadIdx.x & 15;
    int f0 = l * 4;
    int n  = (blockIdx.x * 256 + threadIdx.x) >> 4;   // stream id

    float4 wa = *(const float4*)(wattn + f0);

    int i   = offs[n];
    int end = offs[n + 1];
    while (n < N_NODE) {
        int nn = n + NSTREAM;
        int ni = 0, ne = 0;
        if (nn < N_NODE) { ni = offs[nn]; ne = offs[nn + 1]; }

        float4 acc = make_float4(0.f, 0.f, 0.f, 0.f);
        int2 e[4];
        #pragma unroll
        for (int j = 0; j < 4; ++j) e[j] = csr3[i + j];
        while (i < end) {
            int2 p[4];
            #pragma unroll
            for (int j = 0; j < 4; ++j) p[j] = csr3[i + 4 + j];

            uint4 hv[4];
            uint2 up[4], uq[4], ua[4];
            #pragma unroll
            for (int j = 0; j < 4; ++j) {
                unsigned ex = (unsigned)e[j].x, ey = (unsigned)e[j].y;
                unsigned sub = ex & 0x1FFFFu;
                unsigned rl  = ey & 0x1FFu;
                unsigned ri  = (ey >> 9) & 0xFFu;
                hv[j] = *(const uint4*)(hh + (sub << 7) + l * 8);
                up[j] = *(const uint2*)(rel_preb + (rl << 6) + f0);
                uq[j] = *(const uint2*)(qr_preb  + (ri << 6) + f0);
                ua[j] = *(const uint2*)(relab    + (rl << 6) + f0);
            }
            #pragma unroll
            for (int j = 0; j < 4; ++j) {
                float t =  fmaxf(bflo(hv[j].x) + bflo(up[j].x) + bflo(uq[j].x), 0.f) * wa.x;
                t = fmaf(fmaxf(bfhi(hv[j].x) + bfhi(up[j].x) + bfhi(uq[j].x), 0.f), wa.y, t);
                t = fmaf(fmaxf(bflo(hv[j].y) + bflo(up[j].y) + bflo(uq[j].y), 0.f), wa.z, t);
                t = fmaf(fmaxf(bfhi(hv[j].y) + bfhi(up[j].y) + bfhi(uq[j].y), 0.f), wa.w, t);
                t += __shfl_xor(t, 1);
                t += __shfl_xor(t, 2);
                t += __shfl_xor(t, 4);
                t += __shfl_xor(t, 8);
                float v  = (i + j < end) ? 1.0f : 0.0f;
                float al = v / (1.0f + __expf(-t));
                acc.x = fmaf(al, bflo(hv[j].z) + bflo(ua[j].x), acc.x);
                acc.y = fmaf(al, bfhi(hv[j].z) + bfhi(ua[j].x), acc.y);
                acc.z = fmaf(al, bflo(hv[j].w) + bflo(ua[j].y), acc.z);
                acc.w = fmaf(al, bfhi(hv[j].w) + bfhi(ua[j].y), acc.w);
            }
            #pragma unroll
            for (int j = 0; j < 4; ++j) e[j] = p[j];
            i += 4;
        }

        uint2 o;
        o.x = (unsigned)f2bf_rne(acc.x) | ((unsigned)f2bf_rne(acc.y) << 16);
        o.y = (unsigned)f2bf_rne(acc.z) | ((unsigned)f2bf_rne(acc.w) << 16);
        *(uint2*)(aggb + (((unsigned)n) << 6) + f0) = o;

        n = nn; i = ni; end = ne;
    }
}

// ---------------------------------------------------------------------------
// Fallback (ws too small): wave-per-edge atomic kernel, bf16 tables.
// ---------------------------------------------------------------------------
__global__ __launch_bounds__(256) void edge_kernel(
    const int*      __restrict__ edges,
    const ushort_t* __restrict__ hB,
    const ushort_t* __restrict__ relab,
    const ushort_t* __restrict__ hsWs,
    const ushort_t* __restrict__ rel_preb,
    const ushort_t* __restrict__ qr_preb,
    const float*    __restrict__ wattn,
    float* __restrict__ out)
{
    int e = (blockIdx.x * blockDim.x + threadIdx.x) >> 6;
    if (e >= N_EDGE) return;
    int lane = threadIdx.x & 63;
    int r_i = edges[e * 6 + 0];
    int rl  = edges[e * 6 + 2];
    int sb  = edges[e * 6 + 4];
    int ob  = edges[e * 6 + 5];
    float hs = __uint_as_float(((unsigned)hB[(size_t)sb * DIM + lane]) << 16);
    float hr = __uint_as_float(((unsigned)relab[(size_t)rl * DIM + lane]) << 16);
    float p1 = __uint_as_float(((unsigned)hsWs[(size_t)sb * DIM + lane]) << 16);
    float p2 = __uint_as_float(((unsigned)rel_preb[(size_t)rl * DIM + lane]) << 16);
    float p3 = __uint_as_float(((unsigned)qr_preb[(size_t)r_i * DIM + lane]) << 16);
    float t = wattn[lane] * fmaxf(p1 + p2 + p3, 0.0f);
    #pragma unroll
    for (int off = 32; off; off >>= 1) t += __shfl_xor(t, off);
    float alpha = 1.0f / (1.0f + __expf(-t));
    atomicAdd(&out[(size_t)ob * DIM + lane], (hs + hr) * alpha);
}

extern "C" void kernel_launch(void* const* d_in, const int* in_sizes, int n_in,
                              void* d_out, int out_size, void* d_ws, size_t ws_size,
                              hipStream_t stream)
{
    const float* hidden = (const float*)d_in[0];
    const int*   q_rel  = (const int*)  d_in[1];
    const int*   edges  = (const int*)  d_in[2];
    const float* rela   = (const float*)d_in[3];
    const float* Ws     = (const float*)d_in[4];
    const float* Wr     = (const float*)d_in[5];
    const float* Wqr    = (const float*)d_in[6];
    const float* Wqr_b  = (const float*)d_in[7];
    const float* Wattn  = (const float*)d_in[8];
    const float* Wh     = (const float*)d_in[9];
    float* out = (float*)d_out;

    // ---- workspace layout (~51MB) ----
    ushort_t* qr_preb  = (ushort_t*)d_ws;                 // 256*64 bf16
    ushort_t* rel_preb = qr_preb + NB * DIM;              // 401*64 bf16
    ushort_t* relab    = rel_preb + NVOCAB * DIM;         // 401*64 bf16
    ushort_t* hh       = relab + NVOCAB * DIM;            // 100000*128 bf16 (25.6MB)
    int2* epack  = (int2*)(((uintptr_t)(hh + (size_t)N_NODE * 128) + 15) & ~(uintptr_t)15);
    int*  histBB = (int*)(epack + N_EDGE);                // NCHK*NBKT (0.77MB)
    int*  offs2  = histBB + SCAN_TOT;                     // NCHK*NBKT (0.77MB)
    int*  partialA = offs2 + SCAN_TOT;                    // 1024
    int*  bstart   = partialA + 1024;                     // NBKT+1
    int2* csr2   = (int2*)(((uintptr_t)(bstart + NBKT + 1) + 15) & ~(uintptr_t)15);
    ushort_t* wsp = (ushort_t*)(csr2 + N_EDGE);           // 4*2*4096 bf16 (64KB)
    int2* csr3   = (int2*)(wsp + 4 * 8192);               // N_EDGE+32 (8MB)
    int*  offs   = (int*)(csr3 + N_EDGE + 32);            // N_NODE+1
    size_t csr_need = ((char*)(offs + N_NODE + 1)) - (char*)d_ws;
    bool use_csr = ws_size >= csr_need;
    // aggb (12.8MB) aliases epack(8MB)+histBB+offs2+partialA+bstart(~1.6MB)
    // +csr2 head -- all dead after node_sort; wsp/csr3/offs start ~17.6MB in,
    // beyond aggb's 12.8MB reach.
    ushort_t* aggb = (ushort_t*)epack;

    if (use_csr) {
        init_kernel<<<INIT_GRID, 256, 0, stream>>>(Ws, Wr, Wqr, Wh, wsp);
        prepcount_kernel<<<PREPC_GRID, 256, 0, stream>>>(
            hidden, rela, q_rel, wsp, Wqr_b,
            hh, rel_preb, relab, qr_preb, edges, epack, histBB);
        scanA_kernel<<<SCANA_GRID, 1024, 0, stream>>>(histBB, offs2, partialA);
        scanC_kernel<<<SCANA_GRID, 1024, 0, stream>>>(offs2, partialA, bstart);
        scatter_kernel<<<NCHK, 256, 0, stream>>>(epack, offs2, csr2);
        node_sort_kernel<<<NBKT, 512, 0, stream>>>(csr2, bstart, csr3, offs);
        agg_kernel<<<AGG_WAVES / 4, 256, 0, stream>>>(
            csr3, offs, hh, rel_preb, qr_preb, relab, Wattn, aggb);
        gemm64p_bf16A_kernel<<<(N_NODE + 63) / 64, 256, 0, stream>>>(
            aggb, wsp + 3 * 8192, wsp + 3 * 8192 + 4096, out, N_NODE);
    } else {
        // fallback reuses the hh region as two separate tables
        ushort_t* hsWs_fb = hh;
        ushort_t* hidb_fb = hh + (size_t)N_NODE * DIM;
        gemm64_kernel<<<(NVOCAB + 63) / 64, 256, 0, stream>>>(
            rela, nullptr, Wr, nullptr, rel_preb, relab, NVOCAB, 3);
        gemm64_kernel<<<(NB + 63) / 64, 256, 0, stream>>>(
            rela, q_rel, Wqr, Wqr_b, qr_preb, nullptr, NB, 2);
        gemm64_kernel<<<(N_NODE + 63) / 64, 256, 0, stream>>>(
            hidden, nullptr, Ws, nullptr, hsWs_fb, hidb_fb, N_NODE, 3);
        hipMemsetAsync(d_out, 0, (size_t)N_NODE * DIM * sizeof(float), stream);
        edge_kernel<<<(N_EDGE + 3) / 4, 256, 0, stream>>>(
            edges, hidb_fb, relab, hsWs_fb, rel_preb, qr_preb, Wattn, out);
        gemm64_kernel<<<(N_NODE + 63) / 64, 256, 0, stream>>>(
            out, nullptr, Wh, nullptr, out, nullptr, N_NODE, 1);
    }
}

// Round 13
// 230.438 us; speedup vs baseline: 1.0169x; 1.0169x over previous
//
#include <hip/hip_runtime.h>
#include <math.h>
#include <stdint.h>

#define N_NODE 100000
#define N_EDGE 1000000
#define DIM    64
#define NB     256
#define NVOCAB 401
#define AGG_WAVES 8192
#define NSTREAM (AGG_WAVES * 4)           // quarter-wave node streams

// bucket decomposition: bucket = obj >> 9 (512 nodes/bucket).
#define BSH    9
#define BMSK   511
#define NBKT   ((N_NODE + BMSK) >> BSH)   // 196
#define CHKE   1024                       // edges per chunk
#define NCHK   ((N_EDGE + CHKE - 1) / CHKE)   // 977
#define SCAN_TOT (NBKT * NCHK)            // 191492
#define SCANA_GRID ((SCAN_TOT + 1023) / 1024) // 188

typedef short short8  __attribute__((ext_vector_type(8)));
typedef float floatx4 __attribute__((ext_vector_type(4)));
typedef unsigned short ushort_t;

__device__ inline unsigned short f2bf_rne(float f)
{
    unsigned u = __float_as_uint(f);
    unsigned r = u + 0x7FFF + ((u >> 16) & 1);
    return (unsigned short)(r >> 16);
}
__device__ inline float bflo(unsigned u) { return __uint_as_float(u << 16); }
__device__ inline float bfhi(unsigned u) { return __uint_as_float(u & 0xFFFF0000u); }
__device__ inline unsigned short f2h(float f)
{
    _Float16 h = (_Float16)f;
    unsigned short s; __builtin_memcpy(&s, &h, 2); return s;
}
__device__ inline float h2f(unsigned b)
{
    unsigned short s = (unsigned short)b;
    _Float16 h; __builtin_memcpy(&h, &s, 2); return (float)h;
}

__device__ inline void split8(float4 v0, float4 v1, short8& hi, short8& lo)
{
    float f[8] = {v0.x, v0.y, v0.z, v0.w, v1.x, v1.y, v1.z, v1.w};
    #pragma unroll
    for (int j = 0; j < 8; ++j) {
        unsigned u = __float_as_uint(f[j]);
        unsigned r = u + 0x7FFF + ((u >> 16) & 1);
        unsigned short h = (unsigned short)(r >> 16);
        float hf = __uint_as_float(((unsigned)h) << 16);
        float l  = f[j] - hf;
        unsigned u2 = __float_as_uint(l);
        unsigned r2 = u2 + 0x7FFF + ((u2 >> 16) & 1);
        hi[j] = (short)h;
        lo[j] = (short)(r2 >> 16);
    }
}

// ---------------------------------------------------------------------------
// init: pre-split the 4 weight matrices into bf16 hi/lo tables.
// ---------------------------------------------------------------------------
#define INIT_GRID ((4 * 4096 + 255) / 256)

__global__ __launch_bounds__(256) void init_kernel(
    const float* __restrict__ Ws, const float* __restrict__ Wr,
    const float* __restrict__ Wqr, const float* __restrict__ Wh,
    ushort_t* __restrict__ wsp)
{
    int tid = blockIdx.x * 256 + threadIdx.x;
    if (tid < 4 * 4096) {
        int w = tid >> 12, e = tid & 4095;
        const float* src = (w == 0) ? Ws : (w == 1) ? Wr : (w == 2) ? Wqr : Wh;
        float f = src[e];
        unsigned u = __float_as_uint(f);
        unsigned r = u + 0x7FFF + ((u >> 16) & 1);
        unsigned short h = (unsigned short)(r >> 16);
        float hf = __uint_as_float(((unsigned)h) << 16);
        float l  = f - hf;
        unsigned u2 = __float_as_uint(l);
        unsigned r2 = u2 + 0x7FFF + ((u2 >> 16) & 1);
        wsp[w * 8192 + e]        = h;
        wsp[w * 8192 + 4096 + e] = (unsigned short)(r2 >> 16);
    }
}

// ---------------------------------------------------------------------------
// gemm64p body (fp32 A, PRE-SPLIT bf16 W). Swapped operands -> packed stores.
// out_mode: 0 fp32 | 1 fp32+relu | 2 bf16 | 3 bf16 + bf16(X) copy to Y2.
// ---------------------------------------------------------------------------
__device__ void gemm64p_body(
    const float* __restrict__ X,
    const int*   __restrict__ idx,
    const ushort_t* __restrict__ Whi,
    const ushort_t* __restrict__ Wlo,
    const float* __restrict__ bias,
    void* __restrict__ Yv,
    ushort_t* __restrict__ Y2,
    int R, int out_mode, int blk)
{
    int wave = threadIdx.x >> 6;
    int lane = threadIdx.x & 63;
    int m    = lane & 15;
    int quad = lane >> 4;
    int r0   = blk * 64 + wave * 16;

    int r = r0 + m;
    int src = (r < R) ? (idx ? idx[r] : r) : 0;
    const float* xrow = X + (size_t)src * DIM + quad * 8;

    float4 a0[2], a1[2];
    #pragma unroll
    for (int c = 0; c < 2; ++c) {
        a0[c] = *(const float4*)(xrow + 32 * c);
        a1[c] = *(const float4*)(xrow + 32 * c + 4);
    }
    short8 ah[2], al[2];
    #pragma unroll
    for (int c = 0; c < 2; ++c) split8(a0[c], a1[c], ah[c], al[c]);

    if (out_mode == 3 && r < R) {
        #pragma unroll
        for (int c = 0; c < 2; ++c)
            *(short8*)(Y2 + (size_t)r * DIM + 32 * c + quad * 8) = ah[c];
    }

    floatx4 acc[4] = {{0,0,0,0},{0,0,0,0},{0,0,0,0},{0,0,0,0}};
    #pragma unroll
    for (int g = 0; g < 4; ++g) {
        const ushort_t* whrow = Whi + (size_t)(g * 16 + m) * DIM + quad * 8;
        const ushort_t* wlrow = Wlo + (size_t)(g * 16 + m) * DIM + quad * 8;
        #pragma unroll
        for (int c = 0; c < 2; ++c) {
            short8 bh = *(const short8*)(whrow + 32 * c);
            short8 bl = *(const short8*)(wlrow + 32 * c);
            acc[g] = __builtin_amdgcn_mfma_f32_16x16x32_bf16(bh, ah[c], acc[g], 0, 0, 0);
            acc[g] = __builtin_amdgcn_mfma_f32_16x16x32_bf16(bl, ah[c], acc[g], 0, 0, 0);
            acc[g] = __builtin_amdgcn_mfma_f32_16x16x32_bf16(bh, al[c], acc[g], 0, 0, 0);
        }
    }

    if (r < R) {
        #pragma unroll
        for (int g = 0; g < 4; ++g) {
            float4 bv = make_float4(0.f, 0.f, 0.f, 0.f);
            if (bias) bv = *(const float4*)(bias + g * 16 + quad * 4);
            float v0 = acc[g][0] + bv.x;
            float v1 = acc[g][1] + bv.y;
            float v2 = acc[g][2] + bv.z;
            float v3 = acc[g][3] + bv.w;
            if (out_mode == 1) {
                v0 = fmaxf(v0, 0.f); v1 = fmaxf(v1, 0.f);
                v2 = fmaxf(v2, 0.f); v3 = fmaxf(v3, 0.f);
            }
            if (out_mode >= 2) {
                uint2 o;
                o.x = (unsigned)f2bf_rne(v0) | ((unsigned)f2bf_rne(v1) << 16);
                o.y = (unsigned)f2bf_rne(v2) | ((unsigned)f2bf_rne(v3) << 16);
                *(uint2*)((ushort_t*)Yv + (size_t)r * DIM + g * 16 + quad * 4) = o;
            } else {
                *(float4*)((float*)Yv + (size_t)r * DIM + g * 16 + quad * 4) =
                    make_float4(v0, v1, v2, v3);
            }
        }
    }
}

// ---------------------------------------------------------------------------
// Final gemm, bf16 A, pre-split W: Y[r] = relu( A[r] @ W^T ), fp32 out.
// ---------------------------------------------------------------------------
__global__ __launch_bounds__(256) void gemm64p_bf16A_kernel(
    const ushort_t* __restrict__ A,
    const ushort_t* __restrict__ Whi,
    const ushort_t* __restrict__ Wlo,
    float* __restrict__ Y, int R)
{
    int wave = threadIdx.x >> 6;
    int lane = threadIdx.x & 63;
    int m    = lane & 15;
    int quad = lane >> 4;
    int r0   = blockIdx.x * 64 + wave * 16;

    int r = r0 + m;
    int src = (r < R) ? r : 0;
    short8 a8[2];
    #pragma unroll
    for (int c = 0; c < 2; ++c)
        a8[c] = *(const short8*)(A + (size_t)src * DIM + 32 * c + quad * 8);

    floatx4 acc[4] = {{0,0,0,0},{0,0,0,0},{0,0,0,0},{0,0,0,0}};
    #pragma unroll
    for (int g = 0; g < 4; ++g) {
        const ushort_t* whrow = Whi + (size_t)(g * 16 + m) * DIM + quad * 8;
        const ushort_t* wlrow = Wlo + (size_t)(g * 16 + m) * DIM + quad * 8;
        #pragma unroll
        for (int c = 0; c < 2; ++c) {
            short8 bh = *(const short8*)(whrow + 32 * c);
            short8 bl = *(const short8*)(wlrow + 32 * c);
            acc[g] = __builtin_amdgcn_mfma_f32_16x16x32_bf16(bh, a8[c], acc[g], 0, 0, 0);
            acc[g] = __builtin_amdgcn_mfma_f32_16x16x32_bf16(bl, a8[c], acc[g], 0, 0, 0);
        }
    }

    if (r < R) {
        #pragma unroll
        for (int g = 0; g < 4; ++g) {
            *(float4*)(Y + (size_t)r * DIM + g * 16 + quad * 4) =
                make_float4(fmaxf(acc[g][0], 0.f), fmaxf(acc[g][1], 0.f),
                            fmaxf(acc[g][2], 0.f), fmaxf(acc[g][3], 0.f));
        }
    }
}

// ---------------------------------------------------------------------------
// OLD fp32-W gemm body (fallback path only).
// ---------------------------------------------------------------------------
__device__ void gemm64_body(
    const float* __restrict__ X,
    const int*   __restrict__ idx,
    const float* __restrict__ W,
    const float* __restrict__ bias,
    void* __restrict__ Yv,
    ushort_t* __restrict__ Y2,
    int R, int out_mode, int blk)
{
    int wave = threadIdx.x >> 6;
    int lane = threadIdx.x & 63;
    int m    = lane & 15;
    int quad = lane >> 4;
    int r0   = blk * 64 + wave * 16;

    int r = r0 + m;
    int src = (r < R) ? (idx ? idx[r] : r) : 0;
    const float* xrow = X + (size_t)src * DIM + quad * 8;

    float4 a0[2], a1[2];
    #pragma unroll
    for (int c = 0; c < 2; ++c) {
        a0[c] = *(const float4*)(xrow + 32 * c);
        a1[c] = *(const float4*)(xrow + 32 * c + 4);
    }
    short8 ah[2], al[2];
    #pragma unroll
    for (int c = 0; c < 2; ++c) split8(a0[c], a1[c], ah[c], al[c]);

    if (out_mode == 3 && r < R) {
        #pragma unroll
        for (int c = 0; c < 2; ++c)
            *(short8*)(Y2 + (size_t)r * DIM + 32 * c + quad * 8) = ah[c];
    }

    floatx4 acc[4] = {{0,0,0,0},{0,0,0,0},{0,0,0,0},{0,0,0,0}};
    #pragma unroll
    for (int g = 0; g < 4; ++g) {
        const float* wrow = W + (size_t)(g * 16 + m) * DIM + quad * 8;
        #pragma unroll
        for (int c = 0; c < 2; ++c) {
            float4 b0 = *(const float4*)(wrow + 32 * c);
            float4 b1 = *(const float4*)(wrow + 32 * c + 4);
            short8 bh, bl;
            split8(b0, b1, bh, bl);
            acc[g] = __builtin_amdgcn_mfma_f32_16x16x32_bf16(ah[c], bh, acc[g], 0, 0, 0);
            acc[g] = __builtin_amdgcn_mfma_f32_16x16x32_bf16(ah[c], bl, acc[g], 0, 0, 0);
            acc[g] = __builtin_amdgcn_mfma_f32_16x16x32_bf16(al[c], bh, acc[g], 0, 0, 0);
        }
    }

    #pragma unroll
    for (int g = 0; g < 4; ++g) {
        float bv = bias ? bias[g * 16 + m] : 0.0f;
        #pragma unroll
        for (int reg = 0; reg < 4; ++reg) {
            int rr = r0 + quad * 4 + reg;
            if (rr < R) {
                float v = acc[g][reg] + bv;
                if (out_mode == 1) v = fmaxf(v, 0.0f);
                if (out_mode >= 2)
                    ((ushort_t*)Yv)[(size_t)rr * DIM + g * 16 + m] = f2bf_rne(v);
                else
                    ((float*)Yv)[(size_t)rr * DIM + g * 16 + m] = v;
            }
        }
    }
}

__global__ __launch_bounds__(256) void gemm64_kernel(
    const float* __restrict__ X, const int* __restrict__ idx,
    const float* __restrict__ W, const float* __restrict__ bias,
    void* __restrict__ Yv, ushort_t* __restrict__ Y2, int R, int out_mode)
{
    gemm64_body(X, idx, W, bias, Yv, Y2, R, out_mode, blockIdx.x);
}

// ---------------------------------------------------------------------------
// prepcount: blocks [0,977): edge chunks -> epack + per-chunk LDS histogram
// over 196 obj-buckets (plain stores, ZERO global atomics). Rest: gemms.
// ---------------------------------------------------------------------------
#define G1 ((N_NODE + 63) / 64)            // 1563
#define G2 ((NVOCAB + 63) / 64)            // 7
#define G3 (NB / 64)                       // 4
#define GSMALL (G2 + G3)                   // 11
#define PREPC_GRID (NCHK + GSMALL + G1)    // 2551

__global__ __launch_bounds__(256) void prepcount_kernel(
    const float* __restrict__ hidden,
    const float* __restrict__ rela,
    const int*   __restrict__ q_rel,
    const ushort_t* __restrict__ wsp,
    const float* __restrict__ Wqr_b,
    ushort_t* __restrict__ hsWs,
    ushort_t* __restrict__ hidb,
    ushort_t* __restrict__ rel_preb,
    ushort_t* __restrict__ relab,
    ushort_t* __restrict__ qr_preb,
    const int* __restrict__ edges,
    int2* __restrict__ epack,
    int* __restrict__ histBB)          // [NCHK][NBKT]
{
    int b = blockIdx.x;
    if (b < NCHK) {
        __shared__ unsigned cnt[NBKT];
        if (threadIdx.x < NBKT) cnt[threadIdx.x] = 0;
        __syncthreads();
        int base = b * CHKE + threadIdx.x;
        #pragma unroll
        for (int k = 0; k < 4; ++k) {
            int e = base + k * 256;
            if (e < N_EDGE) {
                int2 ab = *(const int2*)(edges + (size_t)e * 6);      // (r_idx,0)
                int2 cd = *(const int2*)(edges + (size_t)e * 6 + 2);  // (rel,0)
                int2 ef = *(const int2*)(edges + (size_t)e * 6 + 4);  // (sub,obj)
                epack[e] = make_int2(ef.x | (cd.x << 17), ef.y | (ab.x << 17));
                atomicAdd(&cnt[ef.y >> BSH], 1u);                     // LDS only
            }
        }
        __syncthreads();
        if (threadIdx.x < NBKT)
            histBB[b * NBKT + threadIdx.x] = (int)cnt[threadIdx.x];
    } else if (b < NCHK + G2) {
        gemm64p_body(rela, nullptr, wsp + 1 * 8192, wsp + 1 * 8192 + 4096,
                     nullptr, rel_preb, relab, NVOCAB, 3, b - NCHK);
    } else if (b < NCHK + GSMALL) {
        gemm64p_body(rela, q_rel, wsp + 2 * 8192, wsp + 2 * 8192 + 4096,
                     Wqr_b, qr_preb, nullptr, NB, 2, b - NCHK - G2);
    } else {
        gemm64p_body(hidden, nullptr, wsp, wsp + 4096,
                     nullptr, hsWs, hidb, N_NODE, 3, b - NCHK - GSMALL);
    }
}

// ---------------------------------------------------------------------------
// Scan pipeline over histBB (bin-major m = bin*NCHK + chunk).
// ---------------------------------------------------------------------------
__global__ __launch_bounds__(1024) void scanA_kernel(
    const int* __restrict__ histBB, int* __restrict__ offs2,
    int* __restrict__ partialA)
{
    __shared__ int s[1024];
    int t = threadIdx.x;
    int m = blockIdx.x * 1024 + t;
    int v = 0;
    if (m < SCAN_TOT) {
        int bin = m / NCHK, ch = m - bin * NCHK;
        v = histBB[ch * NBKT + bin];
    }
    s[t] = v;
    __syncthreads();
    for (int off = 1; off < 1024; off <<= 1) {
        int add = (t >= off) ? s[t - off] : 0;
        __syncthreads();
        s[t] += add;
        __syncthreads();
    }
    if (m < SCAN_TOT) offs2[m] = s[t] - v;   // local exclusive
    if (t == 1023) partialA[blockIdx.x] = s[1023];
}

__global__ __launch_bounds__(1024) void scanC_kernel(
    int* __restrict__ offs2, const int* __restrict__ partialA,
    int* __restrict__ bstart)
{
    __shared__ int s[1024];
    __shared__ int pbase_s;
    int t = threadIdx.x;
    int pb = (t < (int)blockIdx.x) ? partialA[t] : 0;   // SCANA_GRID <= 1024
    s[t] = pb;
    __syncthreads();
    for (int off = 1024 / 2; off; off >>= 1) {
        if (t < off) s[t] += s[t + off];
        __syncthreads();
    }
    if (t == 0) pbase_s = s[0];
    __syncthreads();
    int pbase = pbase_s;

    int m = blockIdx.x * 1024 + t;
    if (m < SCAN_TOT) {
        int val = offs2[m] + pbase;
        offs2[m] = val;
        int bin = m / NCHK, ch = m - bin * NCHK;
        if (ch == 0) bstart[bin] = val;
    }
    if (blockIdx.x == 0 && t == 0) bstart[NBKT] = N_EDGE;
}

// ---------------------------------------------------------------------------
// alpha + scatter v3: r10 shape (4 edges/quarter-wave, 4 iters, 60% occ)
// + EPACK PREFETCH pipeline: iter k+1's epack loads stream in under iter
// k's gathers+compute, breaking the serial epack->gather two-level latency
// chain (the same prefetch that fixed agg in r3->r4). +8 VGPR.
// Record: w0 = sub | (obj&511)<<17 ; w1 = f16(alpha) | rel<<16.
// ---------------------------------------------------------------------------
__global__ __launch_bounds__(1024) void alpha_scatter_kernel(
    const int2*     __restrict__ epack,
    const int*      __restrict__ offs2,
    const ushort_t* __restrict__ hsWs,
    const ushort_t* __restrict__ rel_preb,
    const ushort_t* __restrict__ qr_preb,
    const float*    __restrict__ wattn,
    int2*           __restrict__ csr2)
{
    __shared__ int offL[NBKT];
    int blk = blockIdx.x;
    if (threadIdx.x < NBKT)
        offL[threadIdx.x] = offs2[threadIdx.x * NCHK + blk];
    __syncthreads();

    int wave = threadIdx.x >> 6;          // 0..15
    int lane = threadIdx.x & 63;
    int q    = lane >> 4;
    int l    = lane & 15;
    int f0   = l * 4;
    float4 wa = *(const float4*)(wattn + f0);

    int ebase = blk * CHKE + wave * 64 + q * 4;

    int2 ep[4];
    #pragma unroll
    for (int j = 0; j < 4; ++j)
        ep[j] = epack[min(ebase + j, N_EDGE - 1)];

    #pragma unroll
    for (int it = 0; it < 4; ++it) {
        int e0 = ebase + it * 16;

        // prefetch next iteration's epack (overlaps this iter's gathers)
        int2 epn[4];
        if (it < 3) {
            #pragma unroll
            for (int j = 0; j < 4; ++j)
                epn[j] = epack[min(e0 + 16 + j, N_EDGE - 1)];
        }

        int   sub[4], rl[4], ob[4];
        float tt[4];
        #pragma unroll
        for (int j = 0; j < 4; ++j) {
            sub[j] = ep[j].x & 0x1FFFF;
            rl[j]  = (int)((unsigned)ep[j].x >> 17);
            ob[j]  = ep[j].y & 0x1FFFF;
            int ri = (int)((unsigned)ep[j].y >> 17);

            uint2 uh = *(const uint2*)(hsWs     + (((unsigned)sub[j]) << 6) + f0);
            uint2 ur = *(const uint2*)(rel_preb + (((unsigned)rl[j])  << 6) + f0);
            uint2 uq = *(const uint2*)(qr_preb  + (((unsigned)ri)     << 6) + f0);

            float s0 =  fmaxf(bflo(uh.x) + bflo(ur.x) + bflo(uq.x), 0.f) * wa.x;
            s0 = fmaf(fmaxf(bfhi(uh.x) + bfhi(ur.x) + bfhi(uq.x), 0.f), wa.y, s0);
            s0 = fmaf(fmaxf(bflo(uh.y) + bflo(ur.y) + bflo(uq.y), 0.f), wa.z, s0);
            s0 = fmaf(fmaxf(bfhi(uh.y) + bfhi(ur.y) + bfhi(uq.y), 0.f), wa.w, s0);
            tt[j] = s0;
        }
        #pragma unroll
        for (int j = 0; j < 4; ++j) {
            tt[j] += __shfl_xor(tt[j], 1);
            tt[j] += __shfl_xor(tt[j], 2);
            tt[j] += __shfl_xor(tt[j], 4);
            tt[j] += __shfl_xor(tt[j], 8);
        }

        if (l < 4) {
            int j = l;
            int e = e0 + j;
            if (e < N_EDGE) {
                float alpha = 1.0f / (1.0f + __expf(-tt[j]));
                int bin  = ob[j] >> BSH;
                int slot = atomicAdd(&offL[bin], 1);      // LDS cursor
                csr2[slot] = make_int2(sub[j] | ((ob[j] & BMSK) << 17),
                    (int)(((unsigned)rl[j] << 16) | f2h(alpha)));
            }
        }

        #pragma unroll
        for (int j = 0; j < 4; ++j) ep[j] = epn[j];
    }
}

// ---------------------------------------------------------------------------
// node_sort: block = bucket (512 nodes, 512 threads). Bucket-sorted csr2 ->
// node-sorted csr3 + per-node offs. LDS counting sort over 512 node slots.
// ---------------------------------------------------------------------------
__global__ __launch_bounds__(512) void node_sort_kernel(
    const int2* __restrict__ csr2,
    const int*  __restrict__ bstart,
    int2* __restrict__ csr3,
    int*  __restrict__ offs)
{
    __shared__ int cnt[512], incl[512];
    int b = blockIdx.x;
    int start = bstart[b];
    int end   = bstart[b + 1];
    int len   = end - start;

    cnt[threadIdx.x] = 0;
    __syncthreads();
    for (int t = threadIdx.x; t < len; t += 512) {
        unsigned x = (unsigned)csr2[start + t].x;
        atomicAdd(&cnt[x >> 17], 1);
    }
    __syncthreads();
    incl[threadIdx.x] = cnt[threadIdx.x];
    __syncthreads();
    for (int off = 1; off < 512; off <<= 1) {
        int add = ((int)threadIdx.x >= off) ? incl[threadIdx.x - off] : 0;
        __syncthreads();
        incl[threadIdx.x] += add;
        __syncthreads();
    }
    {
        int excl = incl[threadIdx.x] - cnt[threadIdx.x];
        int n = (b << BSH) + threadIdx.x;
        if (n < N_NODE) offs[n] = start + excl;
        cnt[threadIdx.x] = excl;           // becomes cursor
    }
    if (b == 0 && threadIdx.x == 0) offs[N_NODE] = N_EDGE;
    if (b == 0 && threadIdx.x < 32) csr3[N_EDGE + threadIdx.x] = make_int2(0, 0);
    __syncthreads();
    for (int t = threadIdx.x; t < len; t += 512) {
        int2 ed = csr2[start + t];
        int row = (int)((unsigned)ed.x >> 17);
        int pos = start + atomicAdd(&cnt[row], 1);
        csr3[pos] = ed;
    }
}

// ---------------------------------------------------------------------------
// Aggregation v9: quarter-wave per node (4 independent streams/wave).
// 16 lanes cover 64 features; 4 edges in flight + prefetch; no cross-lane
// reduce; all 64 lanes store.
// ---------------------------------------------------------------------------
__global__ __launch_bounds__(256) void agg_kernel(
    const int2*     __restrict__ csr3,
    const int*      __restrict__ offs,
    const ushort_t* __restrict__ hB,
    const ushort_t* __restrict__ relab,
    ushort_t* __restrict__ aggb)         // bf16 [N_NODE][64]
{
    int l  = threadIdx.x & 15;
    int f0 = l * 4;
    int n  = (blockIdx.x * 256 + threadIdx.x) >> 4;   // stream id 0..NSTREAM-1

    int i   = offs[n];
    int end = offs[n + 1];
    while (n < N_NODE) {
        int nn = n + NSTREAM;
        int ni = 0, ne = 0;
        if (nn < N_NODE) { ni = offs[nn]; ne = offs[nn + 1]; }

        float4 acc = make_float4(0.f, 0.f, 0.f, 0.f);
        int2 e[4];
        #pragma unroll
        for (int j = 0; j < 4; ++j) e[j] = csr3[i + j];
        while (i < end) {
            int2 p[4];
            #pragma unroll
            for (int j = 0; j < 4; ++j) p[j] = csr3[i + 4 + j];

            uint2 uh[4], ur[4];
            #pragma unroll
            for (int j = 0; j < 4; ++j) {
                unsigned ex = (unsigned)e[j].x, ey = (unsigned)e[j].y;
                uh[j] = *(const uint2*)(hB    + ((ex & 0x1FFFFu) << 6) + f0);
                ur[j] = *(const uint2*)(relab + ((ey >> 16) << 6) + f0);
            }
            #pragma unroll
            for (int j = 0; j < 4; ++j) {
                unsigned ey = (unsigned)e[j].y;
                float v  = (i + j < end) ? 1.0f : 0.0f;
                float al = v * h2f(ey & 0xFFFFu);
                acc.x = fmaf(al, bflo(uh[j].x) + bflo(ur[j].x), acc.x);
                acc.y = fmaf(al, bfhi(uh[j].x) + bfhi(ur[j].x), acc.y);
                acc.z = fmaf(al, bflo(uh[j].y) + bflo(ur[j].y), acc.z);
                acc.w = fmaf(al, bfhi(uh[j].y) + bfhi(ur[j].y), acc.w);
            }
            #pragma unroll
            for (int j = 0; j < 4; ++j) e[j] = p[j];
            i += 4;
        }

        uint2 o;
        o.x = (unsigned)f2bf_rne(acc.x) | ((unsigned)f2bf_rne(acc.y) << 16);
        o.y = (unsigned)f2bf_rne(acc.z) | ((unsigned)f2bf_rne(acc.w) << 16);
        *(uint2*)(aggb + (((unsigned)n) << 6) + f0) = o;

        n = nn; i = ni; end = ne;
    }
}

// ---------------------------------------------------------------------------
// Fallback (ws too small): wave-per-edge atomic kernel, bf16 tables.
// ---------------------------------------------------------------------------
__global__ __launch_bounds__(256) void edge_kernel(
    const int*      __restrict__ edges,
    const ushort_t* __restrict__ hB,
    const ushort_t* __restrict__ relab,
    const ushort_t* __restrict__ hsWs,
    const ushort_t* __restrict__ rel_preb,
    const ushort_t* __restrict__ qr_preb,
    const float*    __restrict__ wattn,
    float* __restrict__ out)
{
    int e = (blockIdx.x * blockDim.x + threadIdx.x) >> 6;
    if (e >= N_EDGE) return;
    int lane = threadIdx.x & 63;
    int r_i = edges[e * 6 + 0];
    int rl  = edges[e * 6 + 2];
    int sb  = edges[e * 6 + 4];
    int ob  = edges[e * 6 + 5];
    float hs = __uint_as_float(((unsigned)hB[(size_t)sb * DIM + lane]) << 16);
    float hr = __uint_as_float(((unsigned)relab[(size_t)rl * DIM + lane]) << 16);
    float p1 = __uint_as_float(((unsigned)hsWs[(size_t)sb * DIM + lane]) << 16);
    float p2 = __uint_as_float(((unsigned)rel_preb[(size_t)rl * DIM + lane]) << 16);
    float p3 = __uint_as_float(((unsigned)qr_preb[(size_t)r_i * DIM + lane]) << 16);
    float t = wattn[lane] * fmaxf(p1 + p2 + p3, 0.0f);
    #pragma unroll
    for (int off = 32; off; off >>= 1) t += __shfl_xor(t, off);
    float alpha = 1.0f / (1.0f + __expf(-t));
    atomicAdd(&out[(size_t)ob * DIM + lane], (hs + hr) * alpha);
}

extern "C" void kernel_launch(void* const* d_in, const int* in_sizes, int n_in,
                              void* d_out, int out_size, void* d_ws, size_t ws_size,
                              hipStream_t stream)
{
    const float* hidden = (const float*)d_in[0];
    const int*   q_rel  = (const int*)  d_in[1];
    const int*   edges  = (const int*)  d_in[2];
    const float* rela   = (const float*)d_in[3];
    const float* Ws     = (const float*)d_in[4];
    const float* Wr     = (const float*)d_in[5];
    const float* Wqr    = (const float*)d_in[6];
    const float* Wqr_b  = (const float*)d_in[7];
    const float* Wattn  = (const float*)d_in[8];
    const float* Wh     = (const float*)d_in[9];
    float* out = (float*)d_out;

    // ---- workspace layout (~51MB) ----
    ushort_t* qr_preb  = (ushort_t*)d_ws;                 // 256*64 bf16
    ushort_t* rel_preb = qr_preb + NB * DIM;              // 401*64 bf16
    ushort_t* relab    = rel_preb + NVOCAB * DIM;         // 401*64 bf16
    ushort_t* hsWs     = relab + NVOCAB * DIM;            // 100000*64 bf16
    ushort_t* hidb     = hsWs + (size_t)N_NODE * DIM;     // 100000*64 bf16
    int2* epack  = (int2*)(((uintptr_t)(hidb + (size_t)N_NODE * DIM) + 15) & ~(uintptr_t)15);
    int*  histBB = (int*)(epack + N_EDGE);                // NCHK*NBKT (0.77MB)
    int*  offs2  = histBB + SCAN_TOT;                     // NCHK*NBKT (0.77MB)
    int*  partialA = offs2 + SCAN_TOT;                    // 1024
    int*  bstart   = partialA + 1024;                     // NBKT+1
    int2* csr2   = (int2*)(((uintptr_t)(bstart + NBKT + 1) + 15) & ~(uintptr_t)15);
    ushort_t* wsp = (ushort_t*)(csr2 + N_EDGE);           // 4*2*4096 bf16 (64KB)
    int2* csr3   = (int2*)(wsp + 4 * 8192);               // N_EDGE+32 (8MB)
    int*  offs   = (int*)(csr3 + N_EDGE + 32);            // N_NODE+1
    size_t csr_need = ((char*)(offs + N_NODE + 1)) - (char*)d_ws;
    bool use_csr = ws_size >= csr_need;
    // aggb (12.8MB) aliases epack(8MB)+histBB+offs2+partialA+bstart(~1.6MB)
    // +csr2 head -- all dead after node_sort; wsp/csr3/offs start ~17.6MB in,
    // beyond aggb's 12.8MB reach.
    ushort_t* aggb = (ushort_t*)epack;

    if (use_csr) {
        init_kernel<<<INIT_GRID, 256, 0, stream>>>(Ws, Wr, Wqr, Wh, wsp);
        prepcount_kernel<<<PREPC_GRID, 256, 0, stream>>>(
            hidden, rela, q_rel, wsp, Wqr_b,
            hsWs, hidb, rel_preb, relab, qr_preb, edges, epack, histBB);
        scanA_kernel<<<SCANA_GRID, 1024, 0, stream>>>(histBB, offs2, partialA);
        scanC_kernel<<<SCANA_GRID, 1024, 0, stream>>>(offs2, partialA, bstart);
        alpha_scatter_kernel<<<NCHK, 1024, 0, stream>>>(
            epack, offs2, hsWs, rel_preb, qr_preb, Wattn, csr2);
        node_sort_kernel<<<NBKT, 512, 0, stream>>>(csr2, bstart, csr3, offs);
        agg_kernel<<<AGG_WAVES / 4, 256, 0, stream>>>(csr3, offs, hidb, relab, aggb);
        gemm64p_bf16A_kernel<<<(N_NODE + 63) / 64, 256, 0, stream>>>(
            aggb, wsp + 3 * 8192, wsp + 3 * 8192 + 4096, out, N_NODE);
    } else {
        gemm64_kernel<<<(NVOCAB + 63) / 64, 256, 0, stream>>>(
            rela, nullptr, Wr, nullptr, rel_preb, relab, NVOCAB, 3);
        gemm64_kernel<<<(NB + 63) / 64, 256, 0, stream>>>(
            rela, q_rel, Wqr, Wqr_b, qr_preb, nullptr, NB, 2);
        gemm64_kernel<<<(N_NODE + 63) / 64, 256, 0, stream>>>(
            hidden, nullptr, Ws, nullptr, hsWs, hidb, N_NODE, 3);
        hipMemsetAsync(d_out, 0, (size_t)N_NODE * DIM * sizeof(float), stream);
        edge_kernel<<<(N_EDGE + 3) / 4, 256, 0, stream>>>(
            edges, hidb, relab, hsWs, rel_preb, qr_preb, Wattn, out);
        gemm64_kernel<<<(N_NODE + 63) / 64, 256, 0, stream>>>(
            out, nullptr, Wh, nullptr, out, nullptr, N_NODE, 1);
    }
}